// Round 10
// baseline (3278.761 us; speedup 1.0000x reference)
//
#include <hip/hip_runtime.h>

// ---------------------------------------------------------------------------
// Model: x:(256,1,96) -> 24-layer biLSTM (scan over batch axis: N=96 rows are
// independent chains, T=256 steps) -> slice n in [48,96) -> 24-layer biLSTM
// (N=48) -> z=h2+x1 -> fc1(1536->1000,relu) -> fc2(1000->48) -> FP32 out.
//
// Round-10: kill the 16x v_readlane h-broadcast (~150 cyc/step of VALU->SGPR
// hazards; R8 showed a chain-step has ~328 cyc serial cost, readlanes the
// biggest block). New scan lane roles: lane l (l&31, halves redundant) owns
// gates r1=l&31 (i/f) and r2=r1+32 (g/o). Gates stored at permuted slot
// s(r)=2*(r&31)+(r>>5) -> one prefetched ds_read_b64/step. After per-lane
// activations, ONE ds_swizzle xor-16 pair (self-inverse, no direction
// ambiguity) gathers partner gates; every lane computes c,h for row j=l&15,
// so each 16-lane row holds the full h vector. Matvec then uses full-rate
// DPP row_ror:k FMAs with per-lane pre-permuted weights W[r][(j-k)&15]
// (loaded once per layer, off-chain). DECLARED RISK: row_ror direction
// (assumed lane i reads lane (i-k)&15); if wrong -> flip to (j+k)&15.
// ---------------------------------------------------------------------------

template <int K>
__device__ __forceinline__ float row_ror(float v) {
  return __int_as_float(__builtin_amdgcn_update_dpp(
      0, __float_as_int(v), 0x120 | K, 0xF, 0xF, true));
}

__device__ __forceinline__ float swz16(float v) {
  // BitMode: and=0x1F, or=0, xor=0x10 -> lane ^ 16 (within each 32-half)
  return __int_as_float(
      __builtin_amdgcn_ds_swizzle(__float_as_int(v), 0x401F));
}

// x1g/h2g: (256,1536) row-major, k = n2*32 + d*16 + j  (n2 = n-48)
__global__ __launch_bounds__(256) void lstm_chain(
    const float* __restrict__ x, const float* __restrict__ W_ih0_1,
    const float* __restrict__ W_ih_1, const float* __restrict__ W_hh_1,
    const float* __restrict__ b_ih_1, const float* __restrict__ b_hh_1,
    const float* __restrict__ W_ih_2, const float* __restrict__ W_hh_2,
    const float* __restrict__ b_ih_2, const float* __restrict__ b_hh_2,
    float* __restrict__ x1g, float* __restrict__ h2g) {
  __shared__ float xgF[256 * 64];  // fwd gates (permuted slots); h_F -> 32..47
  __shared__ float xgB[256 * 64];  // bwd gates (permuted slots); h_B -> 48..63

  const int tid = threadIdx.x;
  const int lane = tid & 63;
  const int w = tid >> 6;
  const int n = blockIdx.x;
  const int nlay = (n < 48) ? 24 : 48;

  const int lh = lane & 31;          // scan: gate-pair role
  const int j16 = lane & 15;         // scan: row owned for c/h
  const bool low = (lane & 16) == 0; // lower row-half: owns (i,gg); upper (f,o)
  // act2 constants: low -> tanh (gate gg), high -> sigmoid (gate o)
  const float s2_ = low ? 2.885390082f : -1.442695041f;
  const float m2_ = low ? -2.0f : 1.0f;
  const float c2_ = low ? 1.0f : 0.0f;
  const int pcol = 2 * lh + (lane >> 5);  // phase-X permuted gate slot

  for (int L = 0; L < nlay; ++L) {
    const bool s2 = (L >= 24);
    const int l = s2 ? (L - 24) : L;
    const float* bih = s2 ? b_ih_2 : b_ih_1;
    const float* bhh = s2 ? b_hh_2 : b_hh_1;
    const float biasF = bih[l * 128 + lane] + bhh[l * 128 + lane];
    const float biasB = bih[l * 128 + 64 + lane] + bhh[l * 128 + 64 + lane];

    // scan-wave Whh loads (pre-permuted k-order), hoisted above phase X.
    // wave w<2 scans direction d=w. w1 -> gate r1=lh, w2 -> gate r2=lh+32.
    float w1[16], w2[16];
    if (w < 2) {
      const float* Whh =
          s2 ? (W_hh_2 + (size_t)l * 2048) : (W_hh_1 + (size_t)l * 2048);
#pragma unroll
      for (int k = 0; k < 16; ++k) {
        const int ks = (j16 - k) & 15;  // RISK: row_ror direction bet
        w1[k] = Whh[((size_t)w * 64 + lh) * 16 + ks];
        w2[k] = Whh[((size_t)w * 64 + lh + 32) * 16 + ks];
      }
    }

    // ---- phase X: gate pre-activations for BOTH directions ----
    if (L == 0) {
      xgF[tid * 64 + 32] = x[(size_t)tid * 96 + n];  // stage x (in_sz=1)
      const float w0F = W_ih0_1[lane];
      const float w0B = W_ih0_1[64 + lane];
      __syncthreads();
      for (int ti = 0; ti < 64; ++ti) {
        const int t = w * 64 + ti;
        const float xs = xgF[t * 64 + 32];  // read precedes write (same wave)
        xgF[t * 64 + pcol] = fmaf(w0F, xs, biasF);
        xgB[t * 64 + pcol] = fmaf(w0B, xs, biasB);
      }
    } else {
      const float* Wih = s2 ? (W_ih_2 + (size_t)l * 4096)
                            : (W_ih_1 + (size_t)(l - 1) * 4096);
      float wf[32], wb[32];
      {
        const float4* wpF =
            reinterpret_cast<const float4*>(Wih + (size_t)lane * 32);
        const float4* wpB =
            reinterpret_cast<const float4*>(Wih + (size_t)(64 + lane) * 32);
#pragma unroll
        for (int q = 0; q < 8; ++q) {
          const float4 a = wpF[q];
          wf[4 * q + 0] = a.x; wf[4 * q + 1] = a.y;
          wf[4 * q + 2] = a.z; wf[4 * q + 3] = a.w;
          const float4 b = wpB[q];
          wb[4 * q + 0] = b.x; wb[4 * q + 1] = b.y;
          wb[4 * q + 2] = b.z; wb[4 * q + 3] = b.w;
        }
      }
      for (int ti = 0; ti < 64; ++ti) {
        const int t = w * 64 + ti;
        const float4* hf4 = reinterpret_cast<const float4*>(&xgF[t * 64 + 32]);
        const float4* hb4 = reinterpret_cast<const float4*>(&xgB[t * 64 + 48]);
        float4 in[8];
#pragma unroll
        for (int q = 0; q < 4; ++q) in[q] = hf4[q];
#pragma unroll
        for (int q = 0; q < 4; ++q) in[4 + q] = hb4[q];
        float a0 = biasF, a1 = 0.f, a2 = 0.f, a3 = 0.f;
        float c0 = biasB, c1 = 0.f, c2 = 0.f, c3 = 0.f;
#pragma unroll
        for (int q = 0; q < 8; ++q) {
          const float4 v = in[q];
          a0 = fmaf(wf[4 * q + 0], v.x, a0);
          a1 = fmaf(wf[4 * q + 1], v.y, a1);
          a2 = fmaf(wf[4 * q + 2], v.z, a2);
          a3 = fmaf(wf[4 * q + 3], v.w, a3);
          c0 = fmaf(wb[4 * q + 0], v.x, c0);
          c1 = fmaf(wb[4 * q + 1], v.y, c1);
          c2 = fmaf(wb[4 * q + 2], v.z, c2);
          c3 = fmaf(wb[4 * q + 3], v.w, c3);
        }
        // reads of row t precede these writes (same wave, in-order DS)
        xgF[t * 64 + pcol] = (a0 + a1) + (a2 + a3);
        xgB[t * 64 + pcol] = (c0 + c1) + (c2 + c3);
      }
    }
    __syncthreads();

    // ---- scans: wave 0 = fwd on xgF, wave 1 = bwd on xgB (concurrent) ----
    if (w < 2) {
      float hreg = 0.f, creg = 0.f;

#define MVK(K, AA, BB)                          \
  {                                             \
    const float rk_ = row_ror<K>(hreg);         \
    AA = fmaf(w1[K], rk_, AA);                  \
    BB = fmaf(w2[K], rk_, BB);                  \
  }

#define LSTM_STEP(XG, CUR, TT, TCOL)                                      \
  {                                                                       \
    float a0 = (CUR).x, a1 = 0.f, a2 = 0.f, a3 = 0.f;                     \
    float b0 = (CUR).y, b1 = 0.f, b2 = 0.f, b3 = 0.f;                     \
    a0 = fmaf(w1[0], hreg, a0);                                           \
    b0 = fmaf(w2[0], hreg, b0);                                           \
    MVK(1, a1, b1) MVK(2, a2, b2) MVK(3, a3, b3)                          \
    MVK(4, a0, b0) MVK(5, a1, b1) MVK(6, a2, b2) MVK(7, a3, b3)           \
    MVK(8, a0, b0) MVK(9, a1, b1) MVK(10, a2, b2) MVK(11, a3, b3)         \
    MVK(12, a0, b0) MVK(13, a1, b1) MVK(14, a2, b2) MVK(15, a3, b3)       \
    const float gv1 = (a0 + a1) + (a2 + a3);                              \
    const float gv2 = (b0 + b1) + (b2 + b3);                              \
    const float e1 = __builtin_amdgcn_exp2f(-1.442695041f * gv1);         \
    const float A1 = __builtin_amdgcn_rcpf(1.0f + e1);                    \
    const float e2 = __builtin_amdgcn_exp2f(s2_ * gv2);                   \
    const float A2 = fmaf(m2_, __builtin_amdgcn_rcpf(1.0f + e2), c2_);    \
    const float S1 = swz16(A1);                                           \
    const float S2 = swz16(A2);                                           \
    const float ig = low ? A1 * A2 : S1 * S2;                             \
    const float ff = low ? S1 : A1;                                       \
    const float oo = low ? S2 : A2;                                       \
    creg = fmaf(ff, creg, ig);                                            \
    const float et = __builtin_amdgcn_exp2f(2.885390082f * creg);         \
    const float th = fmaf(-2.0f, __builtin_amdgcn_rcpf(1.0f + et), 1.0f); \
    hreg = oo * th;                                                       \
    if (lane < 16) XG[(TT)*64 + (TCOL) + lane] = hreg;                    \
  }

#define SCAN_LOOP(XG, DT, T0, TCOL)                                       \
  {                                                                       \
    int t = (T0);                                                         \
    float2 cur0 =                                                         \
        *reinterpret_cast<const float2*>(&XG[t * 64 + 2 * lh]);           \
    float2 cur1 =                                                         \
        *reinterpret_cast<const float2*>(&XG[(t + (DT)) * 64 + 2 * lh]);  \
    for (int tt = 0; tt < 256; tt += 2) {                                 \
      const float2 nx0 = *reinterpret_cast<const float2*>(                \
          &XG[((t + 2 * (DT)) & 255) * 64 + 2 * lh]);                     \
      LSTM_STEP(XG, cur0, t, TCOL)                                        \
      const float2 nx1 = *reinterpret_cast<const float2*>(                \
          &XG[((t + 3 * (DT)) & 255) * 64 + 2 * lh]);                     \
      LSTM_STEP(XG, cur1, t + (DT), TCOL)                                 \
      cur0 = nx0;                                                         \
      cur1 = nx1;                                                         \
      t += 2 * (DT);                                                      \
    }                                                                     \
  }

      if (w == 0) {
        SCAN_LOOP(xgF, 1, 0, 32)
      } else {
        SCAN_LOOP(xgB, -1, 255, 48)
      }
#undef SCAN_LOOP
#undef LSTM_STEP
#undef MVK
    }
    __syncthreads();

    // ---- write-out (block-uniform condition -> conditional sync is safe) --
    if ((L == 23 && n >= 48) || L == 47) {
      float* dst = (L == 23) ? x1g : h2g;
#pragma unroll
      for (int p = 0; p < 8; ++p) {
        const int idx = p * 256 + tid;
        const int t = idx >> 3, q = idx & 7;
        const float4 v =
            (q < 4) ? *reinterpret_cast<const float4*>(&xgF[t * 64 + 32 + q * 4])
                    : *reinterpret_cast<const float4*>(
                          &xgB[t * 64 + 48 + (q - 4) * 4]);
        *reinterpret_cast<float4*>(dst + (size_t)t * 1536 + (n - 48) * 32 +
                                   q * 4) = v;
      }
      __syncthreads();  // next layer's phase X overwrites the cols read above
    }
  }
}

// fc1: y1[b,m] = relu( sum_k (h2[b,k] + x1[b,k]) * w1[m,k] + b1[m] )
// 64x64 tiles, 256 threads, 4x4/thread; k-major LDS; register dbuf.
__global__ __launch_bounds__(256) void fc1_kernel(
    const float* __restrict__ h2,  // (256,1536)
    const float* __restrict__ x1,  // (256,1536)
    const float* __restrict__ w1, const float* __restrict__ b1,
    float* __restrict__ y1) {
  __shared__ float Zs[16][68];
  __shared__ float Ws[16][68];
  const int tid = threadIdx.x;
  const int m0 = blockIdx.x * 64;
  const int b0 = blockIdx.y * 64;
  const int rr = tid >> 2;
  const int c4 = (tid & 3) * 4;
  const int tx = tid & 15, ty = tid >> 4;

  float acc[4][4];
#pragma unroll
  for (int i = 0; i < 4; ++i)
#pragma unroll
    for (int jj = 0; jj < 4; ++jj) acc[i][jj] = 0.f;

  const bool wvalid = (m0 + rr) < 1000;
  const float* zr = h2 + (size_t)(b0 + rr) * 1536 + c4;
  const float* zr2 = x1 + (size_t)(b0 + rr) * 1536 + c4;
  const float* wr = w1 + (size_t)(m0 + rr) * 1536 + c4;

  float4 za = *reinterpret_cast<const float4*>(zr);
  float4 zb = *reinterpret_cast<const float4*>(zr2);
  float4 wv = wvalid ? *reinterpret_cast<const float4*>(wr)
                     : make_float4(0.f, 0.f, 0.f, 0.f);

  for (int k0 = 0; k0 < 1536; k0 += 16) {
    Zs[c4 + 0][rr] = za.x + zb.x;
    Zs[c4 + 1][rr] = za.y + zb.y;
    Zs[c4 + 2][rr] = za.z + zb.z;
    Zs[c4 + 3][rr] = za.w + zb.w;
    Ws[c4 + 0][rr] = wv.x;
    Ws[c4 + 1][rr] = wv.y;
    Ws[c4 + 2][rr] = wv.z;
    Ws[c4 + 3][rr] = wv.w;
    if (k0 + 16 < 1536) {
      za = *reinterpret_cast<const float4*>(zr + k0 + 16);
      zb = *reinterpret_cast<const float4*>(zr2 + k0 + 16);
      if (wvalid) wv = *reinterpret_cast<const float4*>(wr + k0 + 16);
    }
    __syncthreads();
#pragma unroll
    for (int kk = 0; kk < 16; ++kk) {
      const float4 av = *reinterpret_cast<const float4*>(&Zs[kk][ty * 4]);
      const float4 bv = *reinterpret_cast<const float4*>(&Ws[kk][tx * 4]);
      const float a_[4] = {av.x, av.y, av.z, av.w};
      const float b_[4] = {bv.x, bv.y, bv.z, bv.w};
#pragma unroll
      for (int i = 0; i < 4; ++i)
#pragma unroll
        for (int jj = 0; jj < 4; ++jj)
          acc[i][jj] = fmaf(a_[i], b_[jj], acc[i][jj]);
    }
    __syncthreads();
  }
#pragma unroll
  for (int i = 0; i < 4; ++i) {
    const int b = b0 + ty * 4 + i;
#pragma unroll
    for (int jj = 0; jj < 4; ++jj) {
      const int m = m0 + tx * 4 + jj;
      if (m < 1000) {
        const float vo = acc[i][jj] + b1[m];
        y1[(size_t)b * 1000 + m] = vo > 0.f ? vo : 0.f;
      }
    }
  }
}

// fc2: out[b,p] = sum_m y1[b,m]*w2[p,m] + b2[p], p<48; FP32 store.
__global__ __launch_bounds__(64) void fc2_kernel(
    const float* __restrict__ y1, const float* __restrict__ w2,
    const float* __restrict__ b2, float* __restrict__ out) {
  __shared__ float ys[1000];
  const int b = blockIdx.x;
  for (int k = threadIdx.x; k < 1000; k += 64) ys[k] = y1[(size_t)b * 1000 + k];
  __syncthreads();
  const int p = threadIdx.x;
  if (p < 48) {
    float a0 = b2[p], a1 = 0.f, a2 = 0.f, a3 = 0.f;
    const float* wr = w2 + (size_t)p * 1000;
    for (int k = 0; k < 1000; k += 4) {
      const float4 wv = *reinterpret_cast<const float4*>(wr + k);
      a0 = fmaf(ys[k + 0], wv.x, a0);
      a1 = fmaf(ys[k + 1], wv.y, a1);
      a2 = fmaf(ys[k + 2], wv.z, a2);
      a3 = fmaf(ys[k + 3], wv.w, a3);
    }
    out[(size_t)b * 48 + p] = (a0 + a1) + (a2 + a3);
  }
}

extern "C" void kernel_launch(void* const* d_in, const int* in_sizes, int n_in,
                              void* d_out, int out_size, void* d_ws,
                              size_t ws_size, hipStream_t stream) {
  const float* x = (const float*)d_in[0];
  const float* W_ih0_1 = (const float*)d_in[1];
  const float* W_ih_1 = (const float*)d_in[2];
  const float* W_hh_1 = (const float*)d_in[3];
  const float* b_ih_1 = (const float*)d_in[4];
  const float* b_hh_1 = (const float*)d_in[5];
  const float* W_ih_2 = (const float*)d_in[6];
  const float* W_hh_2 = (const float*)d_in[7];
  const float* b_ih_2 = (const float*)d_in[8];
  const float* b_hh_2 = (const float*)d_in[9];
  const float* fc1_w = (const float*)d_in[10];
  const float* fc1_b = (const float*)d_in[11];
  const float* fc2_w = (const float*)d_in[12];
  const float* fc2_b = (const float*)d_in[13];

  float* ws = (float*)d_ws;
  float* x1g = ws;           // 256*1536 = 393216
  float* h2g = ws + 393216;  // 393216
  float* y1 = ws + 786432;   // 256000

  lstm_chain<<<96, 256, 0, stream>>>(x, W_ih0_1, W_ih_1, W_hh_1, b_ih_1,
                                     b_hh_1, W_ih_2, W_hh_2, b_ih_2, b_hh_2,
                                     x1g, h2g);
  fc1_kernel<<<dim3(16, 4), 256, 0, stream>>>(h2g, x1g, fc1_w, fc1_b, y1);
  fc2_kernel<<<256, 64, 0, stream>>>(y1, fc2_w, fc2_b, (float*)d_out);
}